// Round 14
// baseline (126.525 us; speedup 1.0000x reference)
//
#include <hip/hip_runtime.h>

#define VOCAB 50257
#define EMBED 512
#define HID   512
#define B     128
#define SRC   128
#define FBLK2 3142       // fc1 blocks: ceil(50257/16) cols, 16 per 1-wave block

typedef __attribute__((ext_vector_type(8))) short short8;
typedef __attribute__((ext_vector_type(4))) float f32x4;

// f32 -> bf16 (round-to-nearest-even), result in low 16 bits
__device__ __forceinline__ unsigned f2bf(float x) {
    unsigned u = __builtin_bit_cast(unsigned, x);
    return (u + 0x7fffu + ((u >> 16) & 1u)) >> 16;
}
__device__ __forceinline__ unsigned pk2(float lo, float hi) {
    return f2bf(lo) | (f2bf(hi) << 16);
}
__device__ __forceinline__ uint4 pk8(const float* p) {
    uint4 r;
    r.x = pk2(p[0], p[1]); r.y = pk2(p[2], p[3]);
    r.z = pk2(p[4], p[5]); r.w = pk2(p[6], p[7]);
    return r;
}
__device__ __forceinline__ uint4 pk8v(float4 a, float4 b) {
    uint4 r;
    r.x = pk2(a.x, a.y); r.y = pk2(a.z, a.w);
    r.z = pk2(b.x, b.y); r.w = pk2(b.z, b.w);
    return r;
}

// Fragment-packed A layout (bf16, mfma_f32_16x16x32_bf16 A-operand order):
// uint4 index = ((kc*8 + mt)*4 + ksl)*64 + kg*16 + (row&15)
//   row = mt*16 + (row&15), k = kc*128 + ksl*32 + kg*8 + j (j=0..7)

// ---------------------------------------------------------------------------
// K1: pack rnn_in = [emb(x[b]) | ctxv[b]]  (K=1024) and h0[b]  (K=512)
// ---------------------------------------------------------------------------
__global__ void k_embed_pack(const int* __restrict__ x, const float* __restrict__ ctxv,
                             const float* __restrict__ emb, const float* __restrict__ h0,
                             uint4* __restrict__ apk_rnn, uint4* __restrict__ apk_h0) {
    __shared__ float buf[1024];
    __shared__ float hbuf[512];
    const int b = blockIdx.x, t = threadIdx.x;
    const int row = x[b];
    if (t < 128) {
        ((float4*)buf)[t]  = ((const float4*)(emb + (size_t)row * EMBED))[t];
        ((float4*)hbuf)[t] = ((const float4*)(h0 + (size_t)b * HID))[t];
    } else {
        ((float4*)buf)[t] = ((const float4*)(ctxv + (size_t)b * HID))[t - 128];
    }
    __syncthreads();
    const int mt = b >> 4, lb = b & 15;
    if (t < 128) {                       // rnn frag t (K=1024)
        int kc = t >> 4, ksl = (t >> 2) & 3, kg = t & 3;
        apk_rnn[((kc * 8 + mt) * 4 + ksl) * 64 + kg * 16 + lb] = pk8(&buf[t * 8]);
    } else if (t < 192) {                // h0 frag (K=512)
        int i = t - 128;
        int kc = i >> 4, ksl = (i >> 2) & 3, kg = i & 3;
        apk_h0[((kc * 8 + mt) * 4 + ksl) * 64 + kg * 16 + lb] = pk8(&hbuf[i * 8]);
    }
}

// ---------------------------------------------------------------------------
// K2a: MERGED gi/gh GEMM (both N=1536): blocks [0,96) gi (K=1024),
// blocks [96,192) gh (K=512). 4-wave k-split, runtime K.
// ---------------------------------------------------------------------------
__global__ __launch_bounds__(256, 2) void k_gemm2(
        const uint4* __restrict__ apkA, const float* __restrict__ WA,
        const float* __restrict__ bA, float* __restrict__ CA, int KA,
        const uint4* __restrict__ apkB, const float* __restrict__ WB,
        const float* __restrict__ bB, float* __restrict__ CB, int KB,
        int nblkA) {
    const bool isB = (int)blockIdx.x >= nblkA;
    const uint4* apk = isB ? apkB : apkA;
    const float* W   = isB ? WB : WA;
    const float* bias= isB ? bB : bA;
    float* C         = isB ? CB : CA;
    const int K      = isB ? KB : KA;
    const int bid    = isB ? (int)blockIdx.x - nblkA : (int)blockIdx.x;
    const int N = 1536;
    __shared__ float red[4][128][16];          // 32KB
    const int tid = threadIdx.x, lane = tid & 63, wv = tid >> 6;
    const int n0 = bid * 16;
    const int ncol = n0 + (lane & 15);         // < 1536 always
    const int kg = lane >> 4;
    const int spw = K >> 7;                    // slices per wave (8 or 4)
    f32x4 acc[8];
#pragma unroll
    for (int mt = 0; mt < 8; ++mt) acc[mt] = (f32x4)0.f;
    const float4* W4 = (const float4*)W;
    const size_t wb = (size_t)ncol * (K >> 2) + kg * 2;
    for (int s = 0; s < spw; ++s) {
        const int ks = wv * spw + s;
        float4 w0 = W4[wb + ks * 8];
        float4 w1 = W4[wb + ks * 8 + 1];
        short8 bf = __builtin_bit_cast(short8, pk8v(w0, w1));
        const uint4* ap = apk + ((size_t)(ks >> 2) * 32 + (ks & 3)) * 64 + lane;
#pragma unroll
        for (int mt = 0; mt < 8; ++mt) {
            short8 af = __builtin_bit_cast(short8, ap[mt * 256]);
            acc[mt] = __builtin_amdgcn_mfma_f32_16x16x32_bf16(af, bf, acc[mt], 0, 0, 0);
        }
    }
#pragma unroll
    for (int mt = 0; mt < 8; ++mt)
#pragma unroll
        for (int j = 0; j < 4; ++j)
            red[wv][mt * 16 + kg * 4 + j][lane & 15] = acc[mt][j];
    __syncthreads();
#pragma unroll
    for (int i = 0; i < 8; ++i) {
        int o = tid + i * 256;
        int r = o >> 4, c = o & 15;
        float v = red[0][r][c] + red[1][r][c] + red[2][r][c] + red[3][r][c];
        v += bias[n0 + c];
        C[(size_t)r * N + n0 + c] = v;
    }
}

// ---------------------------------------------------------------------------
// K2b: 4-wave k-split MFMA GEMM (Wa / Wc), compile-time config.
// ---------------------------------------------------------------------------
template <int N, int K, int ACT, int HASB, int PACK>
__global__ __launch_bounds__(256, 2) void k_gemm_ks(
        const uint4* __restrict__ apk, const float* __restrict__ W,
        const float* __restrict__ bias, float* __restrict__ C,
        uint4* __restrict__ apk_out) {
    __shared__ float red[4][128][16];          // 32KB
    const int tid = threadIdx.x, lane = tid & 63, wv = tid >> 6;
    const int n0 = blockIdx.x * 16;
    const int ncol = n0 + (lane & 15);
    const int nc = ncol < N ? ncol : N - 1;
    const int kg = lane >> 4;
    constexpr int SPW = K / 128;               // slices per wave (4 or 8)
    f32x4 acc[8];
#pragma unroll
    for (int mt = 0; mt < 8; ++mt) acc[mt] = (f32x4)0.f;
    const float4* W4 = (const float4*)W;
    const size_t wb = (size_t)nc * (K / 4) + kg * 2;
#pragma unroll
    for (int s = 0; s < SPW; ++s) {
        const int ks = wv * SPW + s;
        float4 w0 = W4[wb + ks * 8];
        float4 w1 = W4[wb + ks * 8 + 1];
        short8 bf = __builtin_bit_cast(short8, pk8v(w0, w1));
        const uint4* ap = apk + (((ks >> 2) * 8) * 4 + (ks & 3)) * 64 + lane;
#pragma unroll
        for (int mt = 0; mt < 8; ++mt) {
            short8 af = __builtin_bit_cast(short8, ap[mt * 256]);
            acc[mt] = __builtin_amdgcn_mfma_f32_16x16x32_bf16(af, bf, acc[mt], 0, 0, 0);
        }
    }
#pragma unroll
    for (int mt = 0; mt < 8; ++mt)
#pragma unroll
        for (int j = 0; j < 4; ++j)
            red[wv][mt * 16 + kg * 4 + j][lane & 15] = acc[mt][j];
    __syncthreads();
#pragma unroll
    for (int i = 0; i < 8; ++i) {
        int o = tid + i * 256;
        int r = o >> 4, c = o & 15;
        float v = red[0][r][c] + red[1][r][c] + red[2][r][c] + red[3][r][c];
        if (HASB) v += bias[n0 + c];
        if (ACT) v = tanhf(v);
        C[(size_t)r * N + n0 + c] = v;
        if (PACK) red[0][r][c] = v;            // own (r,c) slot only
    }
    if constexpr (PACK) {
        __syncthreads();
        int r = tid >> 1, hf = tid & 1;        // 256 frags
        float tmp[8];
#pragma unroll
        for (int z = 0; z < 8; ++z) tmp[z] = red[0][r][hf * 8 + z];
        int k0 = n0 + hf * 8;
        int kc = k0 >> 7, ksl = (k0 >> 5) & 3, kg2 = (k0 >> 3) & 3;
        apk_out[((kc * 8 + (r >> 4)) * 4 + ksl) * 64 + kg2 * 16 + (r & 15)] = pk8(tmp);
    }
}

// ---------------------------------------------------------------------------
// K3: GRU gate combine (r,z,n) + pack h fragments (K=512)
// ---------------------------------------------------------------------------
__global__ void k_gru(const float* __restrict__ gi, const float* __restrict__ gh,
                      const float* __restrict__ h0, float* __restrict__ h,
                      uint4* __restrict__ apk_h) {
    __shared__ float hsh[256];
    const int t = threadIdx.x;
    const int idx = blockIdx.x * 256 + t;
    const int b = blockIdx.x >> 1, half = blockIdx.x & 1;
    const int j = half * 256 + t;
    const float* gib = gi + (size_t)b * 1536;
    const float* ghb = gh + (size_t)b * 1536;
    float ir = gib[j], iz = gib[512 + j], inn = gib[1024 + j];
    float hr = ghb[j], hz = ghb[512 + j], hn = ghb[1024 + j];
    float r = 1.f / (1.f + expf(-(ir + hr)));
    float z = 1.f / (1.f + expf(-(iz + hz)));
    float nn = tanhf(inn + r * hn);
    float hv = (1.f - z) * nn + z * h0[idx];
    h[idx] = hv;
    hsh[t] = hv;
    __syncthreads();
    if (t < 32) {
        int k0 = half * 256 + t * 8;
        int kc = k0 >> 7, ksl = (k0 >> 5) & 3, kg = (k0 >> 3) & 3;
        apk_h[((kc * 8 + (b >> 4)) * 4 + ksl) * 64 + kg * 16 + (b & 15)] = pk8(&hsh[t * 8]);
    }
}

// ---------------------------------------------------------------------------
// K4: attention (512 threads)
// ---------------------------------------------------------------------------
__global__ __launch_bounds__(512) void k_attn(const float* __restrict__ enc,
        const float* __restrict__ q, const int* __restrict__ lens,
        const float* __restrict__ h, float* __restrict__ a_out,
        uint4* __restrict__ apk_cat) {
    __shared__ float qs[512];
    __shared__ float red[128];
    __shared__ float aw[128];
    __shared__ float catsh[1024];
    const int b = blockIdx.x, t = threadIdx.x;
    qs[t] = q[(size_t)b * 512 + t];
    __syncthreads();
    const int srow = t >> 2, part = t & 3;
    const float* ep = enc + ((size_t)b * SRC + srow) * 512 + part * 128;
    float s = 0.f;
#pragma unroll
    for (int k4 = 0; k4 < 32; ++k4) {
        float4 e = ((const float4*)ep)[k4];
        float4 qq = *(const float4*)&qs[part * 128 + k4 * 4];
        s = fmaf(e.x, qq.x, fmaf(e.y, qq.y, fmaf(e.z, qq.z, fmaf(e.w, qq.w, s))));
    }
    s += __shfl_xor(s, 1);
    s += __shfl_xor(s, 2);
    if (part == 0) {
        int len = lens[b];
        float val = (srow < len) ? s : 0.f;
        if (val == 0.f) val = -1e10f;   // replicate ref's where(masked==0,-1e10)
        red[srow] = val;
        aw[srow] = val;
    }
    __syncthreads();
    for (int off = 64; off > 0; off >>= 1) {          // max tree
        if (t < off) red[t] = fmaxf(red[t], red[t + off]);
        __syncthreads();
    }
    float mx = red[0];
    __syncthreads();
    if (t < 128) { float e = expf(aw[t] - mx); aw[t] = e; red[t] = e; }
    __syncthreads();
    for (int off = 64; off > 0; off >>= 1) {          // sum tree
        if (t < off) red[t] += red[t + off];
        __syncthreads();
    }
    float denom = red[0];
    if (t < 128) {
        float av = aw[t] / denom;
        aw[t] = av;
        a_out[(size_t)t * B + b] = av;                // layout [S][B]
    }
    __syncthreads();
    float a0 = 0.f;
    const float* e2 = enc + (size_t)b * (SRC * 512) + t;
#pragma unroll 4
    for (int s2 = 0; s2 < SRC; ++s2) a0 = fmaf(aw[s2], e2[(size_t)s2 * 512], a0);
    catsh[t] = a0;
    catsh[512 + t] = h[(size_t)b * 512 + t];
    __syncthreads();
    if (t < 128) {                                    // pack cat frag (K=1024)
        int kc = t >> 4, ksl = (t >> 2) & 3, kg = t & 3;
        apk_cat[((kc * 8 + (b >> 4)) * 4 + ksl) * 64 + kg * 16 + (b & 15)] =
            pk8(&catsh[t * 8]);
    }
}

// ---------------------------------------------------------------------------
// K5: fc1 deep-pipeline direct GEMM with FORCED W burst. 3142 blocks x 1
// wave; wave owns 16 cols x all 128 m x full K=512. The 32-float4 W slice
// is loaded as one burst, then sched_barrier(0) pins the fence so the
// scheduler cannot sink the loads into the consume loop -> wf[32] must be
// register-allocated (128 VGPR) and all 32 loads stay in flight.
// ---------------------------------------------------------------------------
__global__ __launch_bounds__(64, 2) void k_fc1e(
        const uint4* __restrict__ apk, const float* __restrict__ W,
        const float* __restrict__ bias, float* __restrict__ C,
        float2* __restrict__ pout, int nblk) {
    const int lane = threadIdx.x;
    const int kg = lane >> 4;
    const int c0 = blockIdx.x * 16 + (lane & 15);
    const int nc0 = c0 < VOCAB ? c0 : VOCAB - 1;
    const float4* W4 = (const float4*)W;
    const size_t wb = (size_t)nc0 * 128 + kg * 2;

    float4 wf[32];                       // full K=512 W slice for own col
#pragma unroll
    for (int ks = 0; ks < 16; ++ks) {    // 32-load burst, all in flight
        wf[2 * ks]     = W4[wb + ks * 8];
        wf[2 * ks + 1] = W4[wb + ks * 8 + 1];
    }
    __builtin_amdgcn_sched_barrier(0);   // fence: no load may sink below here

    f32x4 acc[8];
#pragma unroll
    for (int mt = 0; mt < 8; ++mt) acc[mt] = (f32x4)0.f;
#pragma unroll
    for (int ks = 0; ks < 16; ++ks) {
        short8 bf = __builtin_bit_cast(short8, pk8v(wf[2 * ks], wf[2 * ks + 1]));
        const uint4* ap = apk + ((size_t)(ks >> 2) * 32 + (ks & 3)) * 64 + lane;
#pragma unroll
        for (int mt = 0; mt < 8; ++mt) {
            short8 af = __builtin_bit_cast(short8, ap[mt * 256]);
            acc[mt] = __builtin_amdgcn_mfma_f32_16x16x32_bf16(af, bf, acc[mt], 0, 0, 0);
        }
    }
    const float bb = bias[nc0];
#pragma unroll
    for (int mt = 0; mt < 8; ++mt) {
#pragma unroll
        for (int j = 0; j < 4; ++j) {
            const int row = mt * 16 + kg * 4 + j;
            float v = acc[mt][j] + bb;
            if (c0 < VOCAB) C[(size_t)row * VOCAB + c0] = v;
            if (pout) {
                float va = c0 < VOCAB ? v : -1e30f;
                float m = va;
                m = fmaxf(m, __shfl_xor(m, 1));
                m = fmaxf(m, __shfl_xor(m, 2));
                m = fmaxf(m, __shfl_xor(m, 4));
                m = fmaxf(m, __shfl_xor(m, 8));
                float e = c0 < VOCAB ? __expf(va - m) : 0.f;
                e += __shfl_xor(e, 1);
                e += __shfl_xor(e, 2);
                e += __shfl_xor(e, 4);
                e += __shfl_xor(e, 8);
                if ((lane & 15) == 0)
                    pout[(size_t)row * nblk + blockIdx.x] = make_float2(m, e);
            }
        }
    }
}

// ---------------------------------------------------------------------------
// K6a: merge per-block LSE partials -> L[row]
// ---------------------------------------------------------------------------
__global__ __launch_bounds__(256) void k_lse_final(const float2* __restrict__ pout,
                                                   float* __restrict__ L, int nblk) {
    const int row = blockIdx.x, t = threadIdx.x;
    float m = -1e30f, s = 0.f;
    for (int i = t; i < nblk; i += 256) {
        float2 p = pout[(size_t)row * nblk + i];
        float mm = fmaxf(m, p.x);
        s = s * __expf(m - mm) + p.y * __expf(p.x - mm);
        m = mm;
    }
    __shared__ float sm[256], ss[256];
    sm[t] = m; ss[t] = s; __syncthreads();
    for (int off = 128; off > 0; off >>= 1) {
        if (t < off) {
            float m2 = sm[t + off], s2 = ss[t + off];
            float mm = fmaxf(sm[t], m2);
            ss[t] = ss[t] * __expf(sm[t] - mm) + s2 * __expf(m2 - mm);
            sm[t] = mm;
        }
        __syncthreads();
    }
    if (t == 0) L[row] = sm[0] + logf(ss[0]);
}

// ---------------------------------------------------------------------------
// K6b: log_probs = logits - L[b]  (in place), full-machine grid
// ---------------------------------------------------------------------------
__global__ __launch_bounds__(512) void k_lsub(float* __restrict__ logits,
                                              const float* __restrict__ L) {
    const int b = blockIdx.y;
    const float l = L[b];
    float* row = logits + (size_t)b * VOCAB;
    int c0 = (blockIdx.x * 512 + threadIdx.x) * 4;
    if (c0 + 4 <= VOCAB) {
        float4 x = *(float4*)(row + c0);
        x.x -= l; x.y -= l; x.z -= l; x.w -= l;
        *(float4*)(row + c0) = x;
    } else {
        for (int c = c0; c < VOCAB; ++c) row[c] -= l;
    }
}

// ---------------------------------------------------------------------------
// K6-fallback: fused log-softmax (online LSE + in-place subtract)
// ---------------------------------------------------------------------------
__global__ __launch_bounds__(1024) void k_lse_sub(float* __restrict__ logits) {
    const int b = blockIdx.x, t = threadIdx.x;
    float* row = logits + (size_t)b * VOCAB;
    const int N4 = VOCAB >> 2;
    float m = -1e30f, s = 0.f;
    for (int i = t; i < N4; i += 1024) {
        float4 x = ((const float4*)row)[i];
        float xs[4] = {x.x, x.y, x.z, x.w};
#pragma unroll
        for (int j = 0; j < 4; ++j) {
            float v = xs[j];
            if (v > m) { s = s * __expf(m - v) + 1.f; m = v; }
            else        s += __expf(v - m);
        }
    }
    if (t == 0) {
        float v = row[VOCAB - 1];
        if (v > m) { s = s * __expf(m - v) + 1.f; m = v; }
        else        s += __expf(v - m);
    }
    __shared__ float sm[1024], ss[1024];
    sm[t] = m; ss[t] = s;
    __syncthreads();
    for (int off = 512; off > 0; off >>= 1) {
        if (t < off) {
            float m2 = sm[t + off], s2 = ss[t + off];
            float mm = fmaxf(sm[t], m2);
            ss[t] = ss[t] * __expf(sm[t] - mm) + s2 * __expf(m2 - mm);
            sm[t] = mm;
        }
        __syncthreads();
    }
    __shared__ float Lsh;
    if (t == 0) Lsh = sm[0] + logf(ss[0]);
    __syncthreads();
    float L = Lsh;
    for (int i = t; i < N4; i += 1024) {
        float4 x = ((const float4*)row)[i];
        x.x -= L; x.y -= L; x.z -= L; x.w -= L;
        ((float4*)row)[i] = x;
    }
    if (t == 0) row[VOCAB - 1] -= L;
}

// ---------------------------------------------------------------------------
extern "C" void kernel_launch(void* const* d_in, const int* in_sizes, int n_in,
                              void* d_out, int out_size, void* d_ws, size_t ws_size,
                              hipStream_t stream) {
    const int*   x    = (const int*)d_in[0];
    const float* h0   = (const float*)d_in[1];   // decoder_hidden [1,B,H]
    const int*   lens = (const int*)d_in[2];
    const float* enc  = (const float*)d_in[3];   // [B,SRC,H]
    const float* ctxv = (const float*)d_in[4];   // [B,H]
    const float* emb  = (const float*)d_in[5];   // [V,E]
    const float* wih  = (const float*)d_in[6];   // [1536,1024]
    const float* whh  = (const float*)d_in[7];   // [1536,512]
    const float* bih  = (const float*)d_in[8];
    const float* bhh  = (const float*)d_in[9];
    const float* Wa   = (const float*)d_in[10];  // [512,512]
    const float* Wc   = (const float*)d_in[11];  // [512,1024]
    const float* fc1w = (const float*)d_in[12];  // [V,512]
    const float* fc1b = (const float*)d_in[13];

    float* out     = (float*)d_out;
    float* outLogp = out;                                  // [B][VOCAB]
    float* outHid  = out + (size_t)B * VOCAB;              // [B][HID]
    float* outA    = outHid + (size_t)B * HID;             // [SRC][B]
    float* outCtx  = outA + (size_t)SRC * B;               // [B][HID]

    // scratch inside the not-yet-written log_probs region (6.43M floats)
    float* gi = outLogp;                                   // [B][1536]
    float* gh = gi + B * 1536;                             // [B][1536]
    float* q  = gh + B * 1536;                             // [B][512]
    uint4* apk_rnn = (uint4*)(q + B * HID);                // 16384 u4 (K=1024)
    uint4* apk_h0  = apk_rnn + 16384;                      // 8192  u4 (K=512)
    uint4* apk_h   = apk_h0 + 8192;                        // 8192  u4 (K=512)
    uint4* apk_cat = apk_h + 8192;                         // 16384 u4 (K=1024)

    uint4*  apk_ctx = (uint4*)d_ws;                        // 128KB (survives fc1)
    size_t  off_pout = 131072;
    size_t  off_L    = off_pout + (size_t)B * FBLK2 * sizeof(float2);
    bool bigws = ws_size >= off_L + 512;
    float2* pout = bigws ? (float2*)((char*)d_ws + off_pout) : nullptr;
    float*  Lb   = bigws ? (float*)((char*)d_ws + off_L) : nullptr;

    k_embed_pack<<<dim3(B), dim3(256), 0, stream>>>(x, ctxv, emb, h0, apk_rnn, apk_h0);
    k_gemm2<<<dim3(192), dim3(256), 0, stream>>>(
        apk_rnn, wih, bih, gi, 1024,
        apk_h0, whh, bhh, gh, 512, 96);
    k_gru<<<dim3(256), dim3(256), 0, stream>>>(gi, gh, h0, outHid, apk_h);
    k_gemm_ks<512, 512, 0, 0, 0><<<dim3(32), dim3(256), 0, stream>>>(
        apk_h, Wa, nullptr, q, nullptr);
    k_attn<<<dim3(B), dim3(512), 0, stream>>>(enc, q, lens, outHid, outA, apk_cat);
    k_gemm_ks<512, 1024, 1, 0, 1><<<dim3(32), dim3(256), 0, stream>>>(
        apk_cat, Wc, nullptr, outCtx, apk_ctx);
    k_fc1e<<<dim3(FBLK2), dim3(64), 0, stream>>>(apk_ctx, fc1w, fc1b, outLogp,
                                                 pout, FBLK2);
    if (bigws) {
        k_lse_final<<<dim3(B), dim3(256), 0, stream>>>(pout, Lb, FBLK2);
        k_lsub<<<dim3(25, B), dim3(512), 0, stream>>>(outLogp, Lb);
    } else {
        k_lse_sub<<<dim3(B), dim3(1024), 0, stream>>>(outLogp);
    }
}

// Round 15
// 123.182 us; speedup vs baseline: 1.0271x; 1.0271x over previous
//
#include <hip/hip_runtime.h>

#define VOCAB 50257
#define EMBED 512
#define HID   512
#define B     128
#define SRC   128
#define FBLK2 3142       // fc1 blocks: ceil(50257/16) cols, 16 per block

typedef __attribute__((ext_vector_type(8))) short short8;
typedef __attribute__((ext_vector_type(4))) float f32x4;

// f32 -> bf16 (round-to-nearest-even), result in low 16 bits
__device__ __forceinline__ unsigned f2bf(float x) {
    unsigned u = __builtin_bit_cast(unsigned, x);
    return (u + 0x7fffu + ((u >> 16) & 1u)) >> 16;
}
__device__ __forceinline__ unsigned pk2(float lo, float hi) {
    return f2bf(lo) | (f2bf(hi) << 16);
}
__device__ __forceinline__ uint4 pk8(const float* p) {
    uint4 r;
    r.x = pk2(p[0], p[1]); r.y = pk2(p[2], p[3]);
    r.z = pk2(p[4], p[5]); r.w = pk2(p[6], p[7]);
    return r;
}
__device__ __forceinline__ uint4 pk8v(float4 a, float4 b) {
    uint4 r;
    r.x = pk2(a.x, a.y); r.y = pk2(a.z, a.w);
    r.z = pk2(b.x, b.y); r.w = pk2(b.z, b.w);
    return r;
}

// Fragment-packed A layout (bf16, mfma_f32_16x16x32_bf16 A-operand order):
// uint4 index = ((kc*8 + mt)*4 + ksl)*64 + kg*16 + (row&15)
//   row = mt*16 + (row&15), k = kc*128 + ksl*32 + kg*8 + j (j=0..7)

// ---------------------------------------------------------------------------
// K1: pack rnn_in = [emb(x[b]) | ctxv[b]]  (K=1024) and h0[b]  (K=512)
// ---------------------------------------------------------------------------
__global__ void k_embed_pack(const int* __restrict__ x, const float* __restrict__ ctxv,
                             const float* __restrict__ emb, const float* __restrict__ h0,
                             uint4* __restrict__ apk_rnn, uint4* __restrict__ apk_h0) {
    __shared__ float buf[1024];
    __shared__ float hbuf[512];
    const int b = blockIdx.x, t = threadIdx.x;
    const int row = x[b];
    if (t < 128) {
        ((float4*)buf)[t]  = ((const float4*)(emb + (size_t)row * EMBED))[t];
        ((float4*)hbuf)[t] = ((const float4*)(h0 + (size_t)b * HID))[t];
    } else {
        ((float4*)buf)[t] = ((const float4*)(ctxv + (size_t)b * HID))[t - 128];
    }
    __syncthreads();
    const int mt = b >> 4, lb = b & 15;
    if (t < 128) {                       // rnn frag t (K=1024)
        int kc = t >> 4, ksl = (t >> 2) & 3, kg = t & 3;
        apk_rnn[((kc * 8 + mt) * 4 + ksl) * 64 + kg * 16 + lb] = pk8(&buf[t * 8]);
    } else if (t < 192) {                // h0 frag (K=512)
        int i = t - 128;
        int kc = i >> 4, ksl = (i >> 2) & 3, kg = i & 3;
        apk_h0[((kc * 8 + mt) * 4 + ksl) * 64 + kg * 16 + lb] = pk8(&hbuf[i * 8]);
    }
}

// ---------------------------------------------------------------------------
// K2a: MERGED gi/gh GEMM (both N=1536): blocks [0,96) gi (K=1024),
// blocks [96,192) gh (K=512). 4-wave k-split, runtime K.
// ---------------------------------------------------------------------------
__global__ __launch_bounds__(256, 2) void k_gemm2(
        const uint4* __restrict__ apkA, const float* __restrict__ WA,
        const float* __restrict__ bA, float* __restrict__ CA, int KA,
        const uint4* __restrict__ apkB, const float* __restrict__ WB,
        const float* __restrict__ bB, float* __restrict__ CB, int KB,
        int nblkA) {
    const bool isB = (int)blockIdx.x >= nblkA;
    const uint4* apk = isB ? apkB : apkA;
    const float* W   = isB ? WB : WA;
    const float* bias= isB ? bB : bA;
    float* C         = isB ? CB : CA;
    const int K      = isB ? KB : KA;
    const int bid    = isB ? (int)blockIdx.x - nblkA : (int)blockIdx.x;
    const int N = 1536;
    __shared__ float red[4][128][16];          // 32KB
    const int tid = threadIdx.x, lane = tid & 63, wv = tid >> 6;
    const int n0 = bid * 16;
    const int ncol = n0 + (lane & 15);         // < 1536 always
    const int kg = lane >> 4;
    const int spw = K >> 7;                    // slices per wave (8 or 4)
    f32x4 acc[8];
#pragma unroll
    for (int mt = 0; mt < 8; ++mt) acc[mt] = (f32x4)0.f;
    const float4* W4 = (const float4*)W;
    const size_t wb = (size_t)ncol * (K >> 2) + kg * 2;
    for (int s = 0; s < spw; ++s) {
        const int ks = wv * spw + s;
        float4 w0 = W4[wb + ks * 8];
        float4 w1 = W4[wb + ks * 8 + 1];
        short8 bf = __builtin_bit_cast(short8, pk8v(w0, w1));
        const uint4* ap = apk + ((size_t)(ks >> 2) * 32 + (ks & 3)) * 64 + lane;
#pragma unroll
        for (int mt = 0; mt < 8; ++mt) {
            short8 af = __builtin_bit_cast(short8, ap[mt * 256]);
            acc[mt] = __builtin_amdgcn_mfma_f32_16x16x32_bf16(af, bf, acc[mt], 0, 0, 0);
        }
    }
#pragma unroll
    for (int mt = 0; mt < 8; ++mt)
#pragma unroll
        for (int j = 0; j < 4; ++j)
            red[wv][mt * 16 + kg * 4 + j][lane & 15] = acc[mt][j];
    __syncthreads();
#pragma unroll
    for (int i = 0; i < 8; ++i) {
        int o = tid + i * 256;
        int r = o >> 4, c = o & 15;
        float v = red[0][r][c] + red[1][r][c] + red[2][r][c] + red[3][r][c];
        v += bias[n0 + c];
        C[(size_t)r * N + n0 + c] = v;
    }
}

// ---------------------------------------------------------------------------
// K2b: 4-wave k-split MFMA GEMM (Wa / Wc), compile-time config.
// ---------------------------------------------------------------------------
template <int N, int K, int ACT, int HASB, int PACK>
__global__ __launch_bounds__(256, 2) void k_gemm_ks(
        const uint4* __restrict__ apk, const float* __restrict__ W,
        const float* __restrict__ bias, float* __restrict__ C,
        uint4* __restrict__ apk_out) {
    __shared__ float red[4][128][16];          // 32KB
    const int tid = threadIdx.x, lane = tid & 63, wv = tid >> 6;
    const int n0 = blockIdx.x * 16;
    const int ncol = n0 + (lane & 15);
    const int nc = ncol < N ? ncol : N - 1;
    const int kg = lane >> 4;
    constexpr int SPW = K / 128;               // slices per wave (4 or 8)
    f32x4 acc[8];
#pragma unroll
    for (int mt = 0; mt < 8; ++mt) acc[mt] = (f32x4)0.f;
    const float4* W4 = (const float4*)W;
    const size_t wb = (size_t)nc * (K / 4) + kg * 2;
#pragma unroll
    for (int s = 0; s < SPW; ++s) {
        const int ks = wv * SPW + s;
        float4 w0 = W4[wb + ks * 8];
        float4 w1 = W4[wb + ks * 8 + 1];
        short8 bf = __builtin_bit_cast(short8, pk8v(w0, w1));
        const uint4* ap = apk + (((ks >> 2) * 8) * 4 + (ks & 3)) * 64 + lane;
#pragma unroll
        for (int mt = 0; mt < 8; ++mt) {
            short8 af = __builtin_bit_cast(short8, ap[mt * 256]);
            acc[mt] = __builtin_amdgcn_mfma_f32_16x16x32_bf16(af, bf, acc[mt], 0, 0, 0);
        }
    }
#pragma unroll
    for (int mt = 0; mt < 8; ++mt)
#pragma unroll
        for (int j = 0; j < 4; ++j)
            red[wv][mt * 16 + kg * 4 + j][lane & 15] = acc[mt][j];
    __syncthreads();
#pragma unroll
    for (int i = 0; i < 8; ++i) {
        int o = tid + i * 256;
        int r = o >> 4, c = o & 15;
        float v = red[0][r][c] + red[1][r][c] + red[2][r][c] + red[3][r][c];
        if (HASB) v += bias[n0 + c];
        if (ACT) v = tanhf(v);
        C[(size_t)r * N + n0 + c] = v;
        if (PACK) red[0][r][c] = v;            // own (r,c) slot only
    }
    if constexpr (PACK) {
        __syncthreads();
        int r = tid >> 1, hf = tid & 1;        // 256 frags
        float tmp[8];
#pragma unroll
        for (int z = 0; z < 8; ++z) tmp[z] = red[0][r][hf * 8 + z];
        int k0 = n0 + hf * 8;
        int kc = k0 >> 7, ksl = (k0 >> 5) & 3, kg2 = (k0 >> 3) & 3;
        apk_out[((kc * 8 + (r >> 4)) * 4 + ksl) * 64 + kg2 * 16 + (r & 15)] = pk8(tmp);
    }
}

// ---------------------------------------------------------------------------
// K3: GRU gate combine (r,z,n) + pack h fragments (K=512)
// ---------------------------------------------------------------------------
__global__ void k_gru(const float* __restrict__ gi, const float* __restrict__ gh,
                      const float* __restrict__ h0, float* __restrict__ h,
                      uint4* __restrict__ apk_h) {
    __shared__ float hsh[256];
    const int t = threadIdx.x;
    const int idx = blockIdx.x * 256 + t;
    const int b = blockIdx.x >> 1, half = blockIdx.x & 1;
    const int j = half * 256 + t;
    const float* gib = gi + (size_t)b * 1536;
    const float* ghb = gh + (size_t)b * 1536;
    float ir = gib[j], iz = gib[512 + j], inn = gib[1024 + j];
    float hr = ghb[j], hz = ghb[512 + j], hn = ghb[1024 + j];
    float r = 1.f / (1.f + expf(-(ir + hr)));
    float z = 1.f / (1.f + expf(-(iz + hz)));
    float nn = tanhf(inn + r * hn);
    float hv = (1.f - z) * nn + z * h0[idx];
    h[idx] = hv;
    hsh[t] = hv;
    __syncthreads();
    if (t < 32) {
        int k0 = half * 256 + t * 8;
        int kc = k0 >> 7, ksl = (k0 >> 5) & 3, kg = (k0 >> 3) & 3;
        apk_h[((kc * 8 + (b >> 4)) * 4 + ksl) * 64 + kg * 16 + (b & 15)] = pk8(&hsh[t * 8]);
    }
}

// ---------------------------------------------------------------------------
// K4: attention (512 threads)
// ---------------------------------------------------------------------------
__global__ __launch_bounds__(512) void k_attn(const float* __restrict__ enc,
        const float* __restrict__ q, const int* __restrict__ lens,
        const float* __restrict__ h, float* __restrict__ a_out,
        uint4* __restrict__ apk_cat) {
    __shared__ float qs[512];
    __shared__ float red[128];
    __shared__ float aw[128];
    __shared__ float catsh[1024];
    const int b = blockIdx.x, t = threadIdx.x;
    qs[t] = q[(size_t)b * 512 + t];
    __syncthreads();
    const int srow = t >> 2, part = t & 3;
    const float* ep = enc + ((size_t)b * SRC + srow) * 512 + part * 128;
    float s = 0.f;
#pragma unroll
    for (int k4 = 0; k4 < 32; ++k4) {
        float4 e = ((const float4*)ep)[k4];
        float4 qq = *(const float4*)&qs[part * 128 + k4 * 4];
        s = fmaf(e.x, qq.x, fmaf(e.y, qq.y, fmaf(e.z, qq.z, fmaf(e.w, qq.w, s))));
    }
    s += __shfl_xor(s, 1);
    s += __shfl_xor(s, 2);
    if (part == 0) {
        int len = lens[b];
        float val = (srow < len) ? s : 0.f;
        if (val == 0.f) val = -1e10f;   // replicate ref's where(masked==0,-1e10)
        red[srow] = val;
        aw[srow] = val;
    }
    __syncthreads();
    for (int off = 64; off > 0; off >>= 1) {          // max tree
        if (t < off) red[t] = fmaxf(red[t], red[t + off]);
        __syncthreads();
    }
    float mx = red[0];
    __syncthreads();
    if (t < 128) { float e = expf(aw[t] - mx); aw[t] = e; red[t] = e; }
    __syncthreads();
    for (int off = 64; off > 0; off >>= 1) {          // sum tree
        if (t < off) red[t] += red[t + off];
        __syncthreads();
    }
    float denom = red[0];
    if (t < 128) {
        float av = aw[t] / denom;
        aw[t] = av;
        a_out[(size_t)t * B + b] = av;                // layout [S][B]
    }
    __syncthreads();
    float a0 = 0.f;
    const float* e2 = enc + (size_t)b * (SRC * 512) + t;
#pragma unroll 4
    for (int s2 = 0; s2 < SRC; ++s2) a0 = fmaf(aw[s2], e2[(size_t)s2 * 512], a0);
    catsh[t] = a0;
    catsh[512 + t] = h[(size_t)b * 512 + t];
    __syncthreads();
    if (t < 128) {                                    // pack cat frag (K=1024)
        int kc = t >> 4, ksl = (t >> 2) & 3, kg = t & 3;
        apk_cat[((kc * 8 + (b >> 4)) * 4 + ksl) * 64 + kg * 16 + (b & 15)] =
            pk8(&catsh[t * 8]);
    }
}

// ---------------------------------------------------------------------------
// K5: fc1 K-SPLIT GEMM — max wave-parallelism. 3142 blocks x 4 waves
// (12568 waves, ~5 blocks/CU LDS-capped). Wave wv computes its K=128 slice
// for 16 cols x all 128 m (4 iters of {2 W loads, 8 L2 A loads, 8 MFMA}).
// Cross-wave combine in LDS + bias + C write + fused LSE partial.
// ---------------------------------------------------------------------------
__global__ __launch_bounds__(256, 4) void k_fc1k(
        const uint4* __restrict__ apk, const float* __restrict__ W,
        const float* __restrict__ bias, float* __restrict__ C,
        float2* __restrict__ pout, int nblk) {
    __shared__ float red[4][128][16];          // 32KB
    const int tid = threadIdx.x, lane = tid & 63, wv = tid >> 6;
    const int n0 = blockIdx.x * 16;
    const int ncol = n0 + (lane & 15);
    const int nc = ncol < VOCAB ? ncol : VOCAB - 1;
    const int kg = lane >> 4;
    f32x4 acc[8];
#pragma unroll
    for (int mt = 0; mt < 8; ++mt) acc[mt] = (f32x4)0.f;
    const float4* W4 = (const float4*)W;
    const size_t wb = (size_t)nc * 128 + kg * 2;
#pragma unroll
    for (int s = 0; s < 4; ++s) {
        const int ks = wv * 4 + s;
        float4 w0 = W4[wb + ks * 8];
        float4 w1 = W4[wb + ks * 8 + 1];
        short8 bf = __builtin_bit_cast(short8, pk8v(w0, w1));
        const uint4* ap = apk + (((ks >> 2) * 8) * 4 + (ks & 3)) * 64 + lane;
#pragma unroll
        for (int mt = 0; mt < 8; ++mt) {
            short8 af = __builtin_bit_cast(short8, ap[mt * 256]);
            acc[mt] = __builtin_amdgcn_mfma_f32_16x16x32_bf16(af, bf, acc[mt], 0, 0, 0);
        }
    }
#pragma unroll
    for (int mt = 0; mt < 8; ++mt)
#pragma unroll
        for (int j = 0; j < 4; ++j)
            red[wv][mt * 16 + kg * 4 + j][lane & 15] = acc[mt][j];
    __syncthreads();
#pragma unroll
    for (int i = 0; i < 8; ++i) {
        int o = tid + i * 256;
        int r = o >> 4, c = o & 15;          // 16 consecutive lanes share row r
        int col = n0 + c;
        bool valid = col < VOCAB;
        float v = red[0][r][c] + red[1][r][c] + red[2][r][c] + red[3][r][c];
        v += bias[valid ? col : VOCAB - 1];
        if (valid) C[(size_t)r * VOCAB + col] = v;
        if (pout) {
            float va = valid ? v : -1e30f;
            float m = va;
            m = fmaxf(m, __shfl_xor(m, 1));
            m = fmaxf(m, __shfl_xor(m, 2));
            m = fmaxf(m, __shfl_xor(m, 4));
            m = fmaxf(m, __shfl_xor(m, 8));
            float e = valid ? __expf(va - m) : 0.f;
            e += __shfl_xor(e, 1);
            e += __shfl_xor(e, 2);
            e += __shfl_xor(e, 4);
            e += __shfl_xor(e, 8);
            if ((lane & 15) == 0)
                pout[(size_t)r * nblk + blockIdx.x] = make_float2(m, e);
        }
    }
}

// ---------------------------------------------------------------------------
// K6a: merge per-block LSE partials -> L[row]
// ---------------------------------------------------------------------------
__global__ __launch_bounds__(256) void k_lse_final(const float2* __restrict__ pout,
                                                   float* __restrict__ L, int nblk) {
    const int row = blockIdx.x, t = threadIdx.x;
    float m = -1e30f, s = 0.f;
    for (int i = t; i < nblk; i += 256) {
        float2 p = pout[(size_t)row * nblk + i];
        float mm = fmaxf(m, p.x);
        s = s * __expf(m - mm) + p.y * __expf(p.x - mm);
        m = mm;
    }
    __shared__ float sm[256], ss[256];
    sm[t] = m; ss[t] = s; __syncthreads();
    for (int off = 128; off > 0; off >>= 1) {
        if (t < off) {
            float m2 = sm[t + off], s2 = ss[t + off];
            float mm = fmaxf(sm[t], m2);
            ss[t] = ss[t] * __expf(sm[t] - mm) + s2 * __expf(m2 - mm);
            sm[t] = mm;
        }
        __syncthreads();
    }
    if (t == 0) L[row] = sm[0] + logf(ss[0]);
}

// ---------------------------------------------------------------------------
// K6b: log_probs = logits - L[b]  (in place), full-machine grid
// ---------------------------------------------------------------------------
__global__ __launch_bounds__(512) void k_lsub(float* __restrict__ logits,
                                              const float* __restrict__ L) {
    const int b = blockIdx.y;
    const float l = L[b];
    float* row = logits + (size_t)b * VOCAB;
    int c0 = (blockIdx.x * 512 + threadIdx.x) * 4;
    if (c0 + 4 <= VOCAB) {
        float4 x = *(float4*)(row + c0);
        x.x -= l; x.y -= l; x.z -= l; x.w -= l;
        *(float4*)(row + c0) = x;
    } else {
        for (int c = c0; c < VOCAB; ++c) row[c] -= l;
    }
}

// ---------------------------------------------------------------------------
// K6-fallback: fused log-softmax (online LSE + in-place subtract)
// ---------------------------------------------------------------------------
__global__ __launch_bounds__(1024) void k_lse_sub(float* __restrict__ logits) {
    const int b = blockIdx.x, t = threadIdx.x;
    float* row = logits + (size_t)b * VOCAB;
    const int N4 = VOCAB >> 2;
    float m = -1e30f, s = 0.f;
    for (int i = t; i < N4; i += 1024) {
        float4 x = ((const float4*)row)[i];
        float xs[4] = {x.x, x.y, x.z, x.w};
#pragma unroll
        for (int j = 0; j < 4; ++j) {
            float v = xs[j];
            if (v > m) { s = s * __expf(m - v) + 1.f; m = v; }
            else        s += __expf(v - m);
        }
    }
    if (t == 0) {
        float v = row[VOCAB - 1];
        if (v > m) { s = s * __expf(m - v) + 1.f; m = v; }
        else        s += __expf(v - m);
    }
    __shared__ float sm[1024], ss[1024];
    sm[t] = m; ss[t] = s;
    __syncthreads();
    for (int off = 512; off > 0; off >>= 1) {
        if (t < off) {
            float m2 = sm[t + off], s2 = ss[t + off];
            float mm = fmaxf(sm[t], m2);
            ss[t] = ss[t] * __expf(sm[t] - mm) + s2 * __expf(m2 - mm);
            sm[t] = mm;
        }
        __syncthreads();
    }
    __shared__ float Lsh;
    if (t == 0) Lsh = sm[0] + logf(ss[0]);
    __syncthreads();
    float L = Lsh;
    for (int i = t; i < N4; i += 1024) {
        float4 x = ((const float4*)row)[i];
        x.x -= L; x.y -= L; x.z -= L; x.w -= L;
        ((float4*)row)[i] = x;
    }
    if (t == 0) row[VOCAB - 1] -= L;
}

// ---------------------------------------------------------------------------
extern "C" void kernel_launch(void* const* d_in, const int* in_sizes, int n_in,
                              void* d_out, int out_size, void* d_ws, size_t ws_size,
                              hipStream_t stream) {
    const int*   x    = (const int*)d_in[0];
    const float* h0   = (const float*)d_in[1];   // decoder_hidden [1,B,H]
    const int*   lens = (const int*)d_in[2];
    const float* enc  = (const float*)d_in[3];   // [B,SRC,H]
    const float* ctxv = (const float*)d_in[4];   // [B,H]
    const float* emb  = (const float*)d_in[5];   // [V,E]
    const float* wih  = (const float*)d_in[6];   // [1536,1024]
    const float* whh  = (const float*)d_in[7];   // [1536,512]
    const float* bih  = (const float*)d_in[8];
    const float* bhh  = (const float*)d_in[9];
    const float* Wa   = (const float*)d_in[10];  // [512,512]
    const float* Wc   = (const float*)d_in[11];  // [512,1024]
    const float* fc1w = (const float*)d_in[12];  // [V,512]
    const float* fc1b = (const float*)d_in[13];

    float* out     = (float*)d_out;
    float* outLogp = out;                                  // [B][VOCAB]
    float* outHid  = out + (size_t)B * VOCAB;              // [B][HID]
    float* outA    = outHid + (size_t)B * HID;             // [SRC][B]
    float* outCtx  = outA + (size_t)SRC * B;               // [B][HID]

    // scratch inside the not-yet-written log_probs region (6.43M floats)
    float* gi = outLogp;                                   // [B][1536]
    float* gh = gi + B * 1536;                             // [B][1536]
    float* q  = gh + B * 1536;                             // [B][512]
    uint4* apk_rnn = (uint4*)(q + B * HID);                // 16384 u4 (K=1024)
    uint4* apk_h0  = apk_rnn + 16384;                      // 8192  u4 (K=512)
    uint4* apk_h   = apk_h0 + 8192;                        // 8192  u4 (K=512)
    uint4* apk_cat = apk_h + 8192;                         // 16384 u4 (K=1024)

    uint4*  apk_ctx = (uint4*)d_ws;                        // 128KB (survives fc1)
    size_t  off_pout = 131072;
    size_t  off_L    = off_pout + (size_t)B * FBLK2 * sizeof(float2);
    bool bigws = ws_size >= off_L + 512;
    float2* pout = bigws ? (float2*)((char*)d_ws + off_pout) : nullptr;
    float*  Lb   = bigws ? (float*)((char*)d_ws + off_L) : nullptr;

    k_embed_pack<<<dim3(B), dim3(256), 0, stream>>>(x, ctxv, emb, h0, apk_rnn, apk_h0);
    k_gemm2<<<dim3(192), dim3(256), 0, stream>>>(
        apk_rnn, wih, bih, gi, 1024,
        apk_h0, whh, bhh, gh, 512, 96);
    k_gru<<<dim3(256), dim3(256), 0, stream>>>(gi, gh, h0, outHid, apk_h);
    k_gemm_ks<512, 512, 0, 0, 0><<<dim3(32), dim3(256), 0, stream>>>(
        apk_h, Wa, nullptr, q, nullptr);
    k_attn<<<dim3(B), dim3(512), 0, stream>>>(enc, q, lens, outHid, outA, apk_cat);
    k_gemm_ks<512, 1024, 1, 0, 1><<<dim3(32), dim3(256), 0, stream>>>(
        apk_cat, Wc, nullptr, outCtx, apk_ctx);
    k_fc1k<<<dim3(FBLK2), dim3(256), 0, stream>>>(apk_ctx, fc1w, fc1b, outLogp,
                                                  pout, FBLK2);
    if (bigws) {
        k_lse_final<<<dim3(B), dim3(256), 0, stream>>>(pout, Lb, FBLK2);
        k_lsub<<<dim3(25, B), dim3(512), 0, stream>>>(outLogp, Lb);
    } else {
        k_lse_sub<<<dim3(B), dim3(1024), 0, stream>>>(outLogp);
    }
}